// Round 3
// baseline (718.234 us; speedup 1.0000x reference)
//
#include <hip/hip_runtime.h>

#define T_SEQ   2048
#define NHEADS  16
#define DHEAD   64
#define DMODEL  1024
#define ALPHA_C 1.4142135f
#define EPS_C   1e-5f

typedef __attribute__((ext_vector_type(8))) short bf16x8;
typedef __attribute__((ext_vector_type(4))) short bf16x4;
typedef __attribute__((ext_vector_type(4))) float floatx4;

__device__ __forceinline__ float bf2f(unsigned short u) {
  union { unsigned int i; float f; } v;
  v.i = ((unsigned int)u) << 16;
  return v.f;
}
__device__ __forceinline__ unsigned short f2bf(float f) {
  union { float f; unsigned int i; } v;
  v.f = f;
  unsigned int u = v.i;
  u += 0x7FFF + ((u >> 16) & 1);   // RNE (finite data only)
  return (unsigned short)(u >> 16);
}

// ---------------------------------------------------------------------------
// GEMM: C[M,N] = A[M,K] @ W[N,K]^T (+ bias[N]); fp32 accum, bf16 MFMA.
// A is f32 (A_F32=true, model inputs) or bf16 (intermediates); W/bias f32
// (weights are f32 inputs); C bf16. f32->bf16 conversion happens during LDS
// staging. 128x128 tile, 4 waves (2x2), 4x4 MFMA 16x16x32 tiles per wave.
// LDS rows padded to 40 elems (80 B). Requires M%128==0, N%128==0, K%32==0.
// ---------------------------------------------------------------------------
template<bool A_F32>
__global__ __launch_bounds__(256) void gemm_bt(
    const void* __restrict__ Ap,
    const float* __restrict__ W,
    unsigned short* __restrict__ C,
    const float* __restrict__ bias,
    int M, int N, int K, int lda)
{
  constexpr int LD = 40;
  __shared__ unsigned short As[128 * LD];
  __shared__ unsigned short Bs[128 * LD];

  const int tid  = threadIdx.x;
  const int lane = tid & 63;
  const int wave = tid >> 6;
  const int wm = (wave >> 1) * 64;
  const int wn = (wave & 1) * 64;
  const int mBase = blockIdx.y * 128;
  const int nBase = blockIdx.x * 128;

  // staging: 2 threads per row, 16 elems each
  const int r0 = tid >> 1;
  const int k0 = (tid & 1) * 16;
  const float*          ag32 = (const float*)Ap          + (size_t)(mBase + r0) * lda + k0;
  const unsigned short* ag16 = (const unsigned short*)Ap + (size_t)(mBase + r0) * lda + k0;
  const float*          wg   = W + (size_t)(nBase + r0) * K + k0;

  floatx4 acc[4][4];
  #pragma unroll
  for (int i = 0; i < 4; i++) {
    #pragma unroll
    for (int j = 0; j < 4; j++) acc[i][j] = (floatx4){0.f, 0.f, 0.f, 0.f};
  }

  const int mrow = lane & 15;
  const int kq   = (lane >> 4) * 8;

  for (int kb = 0; kb < K; kb += 32) {
    bf16x8 av0, av1, bv0, bv1;
    if (A_F32) {
      floatx4 f0 = *(const floatx4*)(ag32 + kb);
      floatx4 f1 = *(const floatx4*)(ag32 + kb + 4);
      floatx4 f2 = *(const floatx4*)(ag32 + kb + 8);
      floatx4 f3 = *(const floatx4*)(ag32 + kb + 12);
      #pragma unroll
      for (int u = 0; u < 4; u++) {
        av0[u]     = (short)f2bf(f0[u]);
        av0[4 + u] = (short)f2bf(f1[u]);
        av1[u]     = (short)f2bf(f2[u]);
        av1[4 + u] = (short)f2bf(f3[u]);
      }
    } else {
      av0 = *(const bf16x8*)(ag16 + kb);
      av1 = *(const bf16x8*)(ag16 + kb + 8);
    }
    {
      floatx4 f0 = *(const floatx4*)(wg + kb);
      floatx4 f1 = *(const floatx4*)(wg + kb + 4);
      floatx4 f2 = *(const floatx4*)(wg + kb + 8);
      floatx4 f3 = *(const floatx4*)(wg + kb + 12);
      #pragma unroll
      for (int u = 0; u < 4; u++) {
        bv0[u]     = (short)f2bf(f0[u]);
        bv0[4 + u] = (short)f2bf(f1[u]);
        bv1[u]     = (short)f2bf(f2[u]);
        bv1[4 + u] = (short)f2bf(f3[u]);
      }
    }
    __syncthreads();  // previous iter's LDS reads done before overwrite
    *(bf16x8*)&As[r0 * LD + k0]     = av0;
    *(bf16x8*)&As[r0 * LD + k0 + 8] = av1;
    *(bf16x8*)&Bs[r0 * LD + k0]     = bv0;
    *(bf16x8*)&Bs[r0 * LD + k0 + 8] = bv1;
    __syncthreads();

    bf16x8 af[4], bfr[4];
    #pragma unroll
    for (int i = 0; i < 4; i++) {
      af[i]  = *(const bf16x8*)&As[(wm + i * 16 + mrow) * LD + kq];
      bfr[i] = *(const bf16x8*)&Bs[(wn + i * 16 + mrow) * LD + kq];
    }
    #pragma unroll
    for (int i = 0; i < 4; i++) {
      #pragma unroll
      for (int j = 0; j < 4; j++)
        acc[i][j] = __builtin_amdgcn_mfma_f32_16x16x32_bf16(af[i], bfr[j], acc[i][j], 0, 0, 0);
    }
  }

  // Epilogue: C/D layout col=lane&15, row=(lane>>4)*4+reg  [verified m89/m91]
  const int col0 = lane & 15;
  const int row0 = (lane >> 4) * 4;
  #pragma unroll
  for (int j = 0; j < 4; j++) {
    const int col = nBase + wn + j * 16 + col0;
    const float badd = bias ? bias[col] : 0.f;
    #pragma unroll
    for (int i = 0; i < 4; i++) {
      #pragma unroll
      for (int r = 0; r < 4; r++) {
        const int row = mBase + wm + i * 16 + row0 + r;
        C[(size_t)row * N + col] = f2bf(acc[i][j][r] + badd);
      }
    }
  }
}

// ---------------------------------------------------------------------------
// RoPE + split: qkv[B,T,3,H,D] (bf16) -> q,k (roped), v in [B*H, T, D] bf16.
// ---------------------------------------------------------------------------
__global__ void rope_split(const unsigned short* __restrict__ qkv,
                           unsigned short* __restrict__ q,
                           unsigned short* __restrict__ k,
                           unsigned short* __restrict__ v)
{
  int gid = blockIdx.x * 256 + threadIdx.x;
  if (gid >= 2 * NHEADS * T_SEQ * 32) return;
  int i  = gid & 31;
  int t  = (gid >> 5) & (T_SEQ - 1);
  int bh = gid >> 16;
  int b = bh >> 4, h = bh & 15;
  size_t inb = ((size_t)(b * T_SEQ + t)) * 3072 + h * DHEAD;
  float fr = powf(10000.f, -(float)i * (1.f / 32.f));
  float ang = (float)t * fr;
  float sn, cs;
  sincosf(ang, &sn, &cs);
  float q1 = bf2f(qkv[inb + i]),        q2 = bf2f(qkv[inb + 32 + i]);
  float k1 = bf2f(qkv[inb + 1024 + i]), k2 = bf2f(qkv[inb + 1024 + 32 + i]);
  size_t ob = ((size_t)bh * T_SEQ + t) * DHEAD + i;
  q[ob]      = f2bf(q1 * cs - q2 * sn);
  q[ob + 32] = f2bf(q2 * cs + q1 * sn);
  k[ob]      = f2bf(k1 * cs - k2 * sn);
  k[ob + 32] = f2bf(k2 * cs + k1 * sn);
  v[ob]      = qkv[inb + 2048 + i];
  v[ob + 32] = qkv[inb + 2048 + 32 + i];
}

// ---------------------------------------------------------------------------
// Banded attention, rel in [-127, 128]. One block = 16 queries of one (b,h).
// K window (<=272 rows) staged in LDS, reused for V in phase 2.
// ---------------------------------------------------------------------------
#define QB  16
#define WKV 272
#define LDK 72

__global__ __launch_bounds__(256) void attn_banded(
    const unsigned short* __restrict__ Qg,
    const unsigned short* __restrict__ Kg,
    const unsigned short* __restrict__ Vg,
    unsigned short* __restrict__ Og)
{
  __shared__ unsigned short kv[WKV * LDK];   // 39168 B
  __shared__ float qs[QB * DHEAD];           //  4096 B
  __shared__ float sc[QB * WKV];             // 17408 B

  const int tid = threadIdx.x;
  const int blk = blockIdx.x;
  const int qt = blk & (T_SEQ / QB - 1);
  const int bh = blk >> 7;
  const int qBase = qt * QB;
  const int lo = max(0, qBase - 127);
  const int hi = min(T_SEQ - 1, qBase + QB - 1 + 128);
  const int nk = hi - lo + 1;
  const size_t hbase = (size_t)bh * T_SEQ * DHEAD;

  const unsigned short* qptr = Qg + hbase + (size_t)qBase * DHEAD;
  for (int idx = tid; idx < QB * DHEAD; idx += 256) qs[idx] = bf2f(qptr[idx]);
  const unsigned short* kptr = Kg + hbase + (size_t)lo * DHEAD;
  const int tot = nk * DHEAD;
  for (int e = tid * 2; e < tot; e += 512) {
    int j = e >> 6, d = e & 63;
    *(unsigned int*)&kv[j * LDK + d] = *(const unsigned int*)&kptr[e];
  }
  __syncthreads();

  const int q  = tid >> 4;
  const int ks = tid & 15;
  const int qg = qBase + q;

  float qreg[DHEAD];
  #pragma unroll
  for (int c4 = 0; c4 < DHEAD / 4; c4++) {
    floatx4 t4 = *(const floatx4*)&qs[q * DHEAD + c4 * 4];
    qreg[c4 * 4 + 0] = t4.x; qreg[c4 * 4 + 1] = t4.y;
    qreg[c4 * 4 + 2] = t4.z; qreg[c4 * 4 + 3] = t4.w;
  }

  float lmax = -3e38f;
  for (int j = ks; j < nk; j += 16) {
    float dot = 0.f;
    #pragma unroll
    for (int c = 0; c < 8; c++) {
      bf16x8 kvv = *(const bf16x8*)&kv[j * LDK + c * 8];
      #pragma unroll
      for (int u = 0; u < 8; u++)
        dot += qreg[c * 8 + u] * bf2f((unsigned short)kvv[u]);
    }
    int kg = lo + j;
    float s = (kg >= qg - 127 && kg <= qg + 128) ? dot * 0.125f : -3e38f;
    sc[q * WKV + j] = s;
    lmax = fmaxf(lmax, s);
  }
  __syncthreads();   // all K reads done -> kv reusable

  const unsigned short* vptr = Vg + hbase + (size_t)lo * DHEAD;
  for (int e = tid * 2; e < tot; e += 512) {
    int j = e >> 6, d = e & 63;
    *(unsigned int*)&kv[j * LDK + d] = *(const unsigned int*)&vptr[e];
  }

  #pragma unroll
  for (int m = 1; m <= 8; m <<= 1) lmax = fmaxf(lmax, __shfl_xor(lmax, m));
  float lsum = 0.f;
  for (int j = ks; j < nk; j += 16) {
    float p = __expf(sc[q * WKV + j] - lmax);
    sc[q * WKV + j] = p;
    lsum += p;
  }
  #pragma unroll
  for (int m = 1; m <= 8; m <<= 1) lsum += __shfl_xor(lsum, m);
  const float inv = 1.f / lsum;
  __syncthreads();   // V staged + all p visible

  float a0 = 0.f, a1 = 0.f, a2 = 0.f, a3 = 0.f;
  const float* pr = &sc[q * WKV];
  for (int j = 0; j < nk; j++) {
    float p = pr[j];
    bf16x4 vv = *(const bf16x4*)&kv[j * LDK + ks * 4];
    a0 += p * bf2f((unsigned short)vv[0]);
    a1 += p * bf2f((unsigned short)vv[1]);
    a2 += p * bf2f((unsigned short)vv[2]);
    a3 += p * bf2f((unsigned short)vv[3]);
  }
  const int b = bh >> 4, h = bh & 15;
  size_t ob = ((size_t)(b * T_SEQ + qg)) * DMODEL + h * DHEAD + ks * 4;
  Og[ob + 0] = f2bf(a0 * inv);
  Og[ob + 1] = f2bf(a1 * inv);
  Og[ob + 2] = f2bf(a2 * inv);
  Og[ob + 3] = f2bf(a3 * inv);
}

// ---------------------------------------------------------------------------
// out = rmsnorm(a + ALPHA*xres, g). a bf16; xres f32 or bf16; g f32;
// out f32 or bf16. One 256-thread block per 1024-dim row.
// ---------------------------------------------------------------------------
template<bool XRES_F32, bool OUT_F32>
__global__ __launch_bounds__(256) void resid_rmsnorm(
    const unsigned short* __restrict__ a,
    const void* __restrict__ xresp,
    const float* __restrict__ g,
    void* __restrict__ outp)
{
  __shared__ float red[4];
  const int row = blockIdx.x;
  const int tid = threadIdx.x;
  const size_t base = (size_t)row * DMODEL;
  float s[4];
  float ss = 0.f;
  #pragma unroll
  for (int r = 0; r < 4; r++) {
    int c = r * 256 + tid;
    float xr = XRES_F32 ? ((const float*)xresp)[base + c]
                        : bf2f(((const unsigned short*)xresp)[base + c]);
    float vv = bf2f(a[base + c]) + ALPHA_C * xr;
    s[r] = vv;
    ss += vv * vv;
  }
  #pragma unroll
  for (int m = 1; m <= 32; m <<= 1) ss += __shfl_xor(ss, m);
  if ((tid & 63) == 0) red[tid >> 6] = ss;
  __syncthreads();
  float ms = (red[0] + red[1] + red[2] + red[3]) * (1.f / DMODEL);
  float scl = rsqrtf(ms + EPS_C);
  #pragma unroll
  for (int r = 0; r < 4; r++) {
    int c = r * 256 + tid;
    float o = s[r] * scl * g[c];
    if (OUT_F32) ((float*)outp)[base + c] = o;
    else ((unsigned short*)outp)[base + c] = f2bf(o);
  }
}

// ---------------------------------------------------------------------------
// SwiGLU in place: yg[r,c] = y * gate * sigmoid(gate), gate = yg[r,4096+c].
// ---------------------------------------------------------------------------
__global__ void swiglu_kernel(unsigned short* __restrict__ yg)
{
  int gid = blockIdx.x * 256 + threadIdx.x;
  int row = gid >> 12, c = gid & 4095;
  size_t b = (size_t)row * 8192;
  float y  = bf2f(yg[b + c]);
  float gt = bf2f(yg[b + 4096 + c]);
  float sig = 1.f / (1.f + __expf(-gt));
  yg[b + c] = f2bf(y * gt * sig);
}

// ---------------------------------------------------------------------------
// Workspace plan (bf16 elems) — peak 46,137,344 elems = 88 MiB:
//   [0,        12.58M)  qkv  (dead after rope_split) -> o / tmp / x2 reuse
//   [12.58M,   25.17M)  q,k,v (dead after attn)      -> yg reuse (33.55M)
// ---------------------------------------------------------------------------
extern "C" void kernel_launch(void* const* d_in, const int* in_sizes, int n_in,
                              void* d_out, int out_size, void* d_ws, size_t ws_size,
                              hipStream_t stream) {
  (void)in_sizes; (void)n_in; (void)out_size; (void)ws_size;
  const float* x    = (const float*)d_in[0];
  const float* Wqkv = (const float*)d_in[1];
  const float* Wout = (const float*)d_in[2];
  const float* bout = (const float*)d_in[3];
  const float* W1   = (const float*)d_in[4];
  const float* W2   = (const float*)d_in[5];
  const float* g1   = (const float*)d_in[6];
  const float* g2   = (const float*)d_in[7];
  float* out = (float*)d_out;

  unsigned short* ws  = (unsigned short*)d_ws;
  unsigned short* qkv = ws;                       // 12,582,912 elems
  unsigned short* q   = ws + 12582912;            //  4,194,304
  unsigned short* k   = ws + 16777216;
  unsigned short* v   = ws + 20971520;
  unsigned short* o   = ws;                       // reuse (qkv dead)
  unsigned short* tmp = ws + 4194304;
  unsigned short* x2  = ws + 8388608;
  unsigned short* yg  = ws + 12582912;            // 33,554,432 (q/k/v dead)

  // 1. qkv = x @ Wqkv^T                          [4096,3072]
  gemm_bt<true><<<dim3(3072 / 128, 4096 / 128), 256, 0, stream>>>(x, Wqkv, qkv, nullptr, 4096, 3072, 1024, 1024);
  // 2. rope + split into q,k,v [B*H,T,64]
  rope_split<<<8192, 256, 0, stream>>>(qkv, q, k, v);
  // 3. banded attention -> o [B,T,1024]
  attn_banded<<<32 * (T_SEQ / QB), 256, 0, stream>>>(q, k, v, o);
  // 4. a = o @ Wout^T + bout -> tmp
  gemm_bt<false><<<dim3(1024 / 128, 4096 / 128), 256, 0, stream>>>(o, Wout, tmp, bout, 4096, 1024, 1024, 1024);
  // 5. x2 = rmsnorm(a + ALPHA*x, g1)   (x is f32, x2 bf16)
  resid_rmsnorm<true, false><<<4096, 256, 0, stream>>>(tmp, x, g1, x2);
  // 6. yg = x2 @ W1^T                            [4096,8192]
  gemm_bt<false><<<dim3(8192 / 128, 4096 / 128), 256, 0, stream>>>(x2, W1, yg, nullptr, 4096, 8192, 1024, 1024);
  // 7. swiglu in place (first 4096 cols of yg)
  swiglu_kernel<<<65536, 256, 0, stream>>>(yg);
  // 8. y2 = ys @ W2^T -> tmp   (A = yg with lda=8192)
  gemm_bt<false><<<dim3(1024 / 128, 4096 / 128), 256, 0, stream>>>(yg, W2, tmp, nullptr, 4096, 1024, 4096, 8192);
  // 9. out = rmsnorm(y2 + ALPHA*x2, g2)  (x2 bf16, out f32)
  resid_rmsnorm<false, true><<<4096, 256, 0, stream>>>(tmp, x2, g2, out);
}

// Round 4
// 573.631 us; speedup vs baseline: 1.2521x; 1.2521x over previous
//
#include <hip/hip_runtime.h>

#define T_SEQ   2048
#define NHEADS  16
#define DHEAD   64
#define DMODEL  1024
#define ALPHA_C 1.4142135f
#define EPS_C   1e-5f

typedef __attribute__((ext_vector_type(8))) short bf16x8;
typedef __attribute__((ext_vector_type(4))) short bf16x4;
typedef __attribute__((ext_vector_type(4))) float floatx4;

__device__ __forceinline__ float bf2f(unsigned short u) {
  union { unsigned int i; float f; } v;
  v.i = ((unsigned int)u) << 16;
  return v.f;
}
__device__ __forceinline__ unsigned short f2bf(float f) {
  union { float f; unsigned int i; } v;
  v.f = f;
  unsigned int u = v.i;
  u += 0x7FFF + ((u >> 16) & 1);   // RNE (finite data only)
  return (unsigned short)(u >> 16);
}

__device__ __forceinline__ void gload_lds16(const void* g, void* l) {
  __builtin_amdgcn_global_load_lds(
      (const __attribute__((address_space(1))) void*)g,
      (__attribute__((address_space(3))) void*)l, 16, 0, 0);
}

// ---------------------------------------------------------------------------
// f32 -> bf16 bulk convert (8 elems/thread, n % 2048 == 0)
// ---------------------------------------------------------------------------
__global__ void f32_to_bf16(const float* __restrict__ in,
                            unsigned short* __restrict__ out)
{
  int i = (blockIdx.x * 256 + threadIdx.x) * 8;
  floatx4 a = *(const floatx4*)(in + i);
  floatx4 b = *(const floatx4*)(in + i + 4);
  bf16x8 o;
  #pragma unroll
  for (int u = 0; u < 4; u++) {
    o[u]     = (short)f2bf(a[u]);
    o[4 + u] = (short)f2bf(b[u]);
  }
  *(bf16x8*)(out + i) = o;
}

// ---------------------------------------------------------------------------
// GEMM (m97 structure): C[M,N] = A[M,K] @ W[N,K]^T (+ bias), all bf16,
// fp32 accum. BM=128, BK=32, BN templated (128 wide / 64 narrow-N shapes).
// Staging via global_load_lds width=16 into UNPADDED row-major LDS tiles
// (lane-order-contiguous, per the wave-uniform-base constraint).
// 4 waves: 2x2 over (128 x BN), wave tile 64 x BN/2, MFMA 16x16x32.
// Requires M%128==0, N%BN==0, K%32==0, lda%8==0.
// ---------------------------------------------------------------------------
template<int BN>
__global__ __launch_bounds__(256) void gemm_lds(
    const unsigned short* __restrict__ A,
    const unsigned short* __restrict__ W,
    unsigned short* __restrict__ C,
    const float* __restrict__ bias,
    int M, int N, int K, int lda)
{
  constexpr int WN = BN / 2;
  constexpr int NJ = WN / 16;
  __shared__ unsigned short As[128 * 32];
  __shared__ unsigned short Bs[BN * 32];

  const int tid  = threadIdx.x;
  const int lane = tid & 63;
  const int wave = tid >> 6;
  const int wm = (wave >> 1) * 64;
  const int wn = (wave & 1) * WN;
  const int mBase = blockIdx.y * 128;
  const int nBase = blockIdx.x * BN;

  // staging geometry: each instr = 64 lanes x 16B = 1KB = 16 rows of 32 bf16
  const int sRow = lane >> 2;          // row-within-16-group
  const int sCol = (lane & 3) * 8;     // k-offset (16B chunk)

  floatx4 acc[4][NJ];
  #pragma unroll
  for (int i = 0; i < 4; i++)
    #pragma unroll
    for (int j = 0; j < NJ; j++) acc[i][j] = (floatx4){0.f, 0.f, 0.f, 0.f};

  const int mrow = lane & 15;
  const int kq   = (lane >> 4) * 8;

  for (int kb = 0; kb < K; kb += 32) {
    __syncthreads();   // prior iteration's LDS reads complete
    // A tile: 128x32 = 8KB -> 8 instrs, 2 per wave
    #pragma unroll
    for (int j = 0; j < 2; j++) {
      int r = wave * 32 + j * 16 + sRow;
      gload_lds16(A + (size_t)(mBase + r) * lda + kb + sCol,
                  &As[wave * 1024 + j * 512 + lane * 8]);
    }
    // B tile
    if constexpr (BN == 128) {
      #pragma unroll
      for (int j = 0; j < 2; j++) {
        int r = wave * 32 + j * 16 + sRow;
        gload_lds16(W + (size_t)(nBase + r) * K + kb + sCol,
                    &Bs[wave * 1024 + j * 512 + lane * 8]);
      }
    } else {
      int r = wave * 16 + sRow;
      gload_lds16(W + (size_t)(nBase + r) * K + kb + sCol,
                  &Bs[wave * 512 + lane * 8]);
    }
    __syncthreads();   // vmcnt(0) drain -> LDS tiles ready

    bf16x8 af[4], bfr[NJ];
    #pragma unroll
    for (int i = 0; i < 4; i++)
      af[i] = *(const bf16x8*)&As[(wm + i * 16 + mrow) * 32 + kq];
    #pragma unroll
    for (int j = 0; j < NJ; j++)
      bfr[j] = *(const bf16x8*)&Bs[(wn + j * 16 + mrow) * 32 + kq];
    #pragma unroll
    for (int i = 0; i < 4; i++)
      #pragma unroll
      for (int j = 0; j < NJ; j++)
        acc[i][j] = __builtin_amdgcn_mfma_f32_16x16x32_bf16(af[i], bfr[j], acc[i][j], 0, 0, 0);
  }

  // Epilogue: C/D layout col=lane&15, row=(lane>>4)*4+reg  [verified m89/m91]
  const int col0 = lane & 15;
  const int row0 = (lane >> 4) * 4;
  #pragma unroll
  for (int j = 0; j < NJ; j++) {
    const int col = nBase + wn + j * 16 + col0;
    const float badd = bias ? bias[col] : 0.f;
    #pragma unroll
    for (int i = 0; i < 4; i++) {
      #pragma unroll
      for (int r = 0; r < 4; r++) {
        const int row = mBase + wm + i * 16 + row0 + r;
        C[(size_t)row * N + col] = f2bf(acc[i][j][r] + badd);
      }
    }
  }
}

// ---------------------------------------------------------------------------
// RoPE + split: qkv[B,T,3,H,D] (bf16) -> q,k (roped), v in [B*H, T, D] bf16.
// ---------------------------------------------------------------------------
__global__ void rope_split(const unsigned short* __restrict__ qkv,
                           unsigned short* __restrict__ q,
                           unsigned short* __restrict__ k,
                           unsigned short* __restrict__ v)
{
  int gid = blockIdx.x * 256 + threadIdx.x;
  if (gid >= 2 * NHEADS * T_SEQ * 32) return;
  int i  = gid & 31;
  int t  = (gid >> 5) & (T_SEQ - 1);
  int bh = gid >> 16;
  int b = bh >> 4, h = bh & 15;
  size_t inb = ((size_t)(b * T_SEQ + t)) * 3072 + h * DHEAD;
  float fr = powf(10000.f, -(float)i * (1.f / 32.f));
  float ang = (float)t * fr;
  float sn, cs;
  sincosf(ang, &sn, &cs);
  float q1 = bf2f(qkv[inb + i]),        q2 = bf2f(qkv[inb + 32 + i]);
  float k1 = bf2f(qkv[inb + 1024 + i]), k2 = bf2f(qkv[inb + 1024 + 32 + i]);
  size_t ob = ((size_t)bh * T_SEQ + t) * DHEAD + i;
  q[ob]      = f2bf(q1 * cs - q2 * sn);
  q[ob + 32] = f2bf(q2 * cs + q1 * sn);
  k[ob]      = f2bf(k1 * cs - k2 * sn);
  k[ob + 32] = f2bf(k2 * cs + k1 * sn);
  v[ob]      = qkv[inb + 2048 + i];
  v[ob + 32] = qkv[inb + 2048 + 32 + i];
}

// ---------------------------------------------------------------------------
// Banded attention, rel in [-127, 128]. One block = 16 queries of one (b,h).
// K window (<=272 rows) staged in LDS, reused for V in phase 2.
// ---------------------------------------------------------------------------
#define QB  16
#define WKV 272
#define LDK 72

__global__ __launch_bounds__(256) void attn_banded(
    const unsigned short* __restrict__ Qg,
    const unsigned short* __restrict__ Kg,
    const unsigned short* __restrict__ Vg,
    unsigned short* __restrict__ Og)
{
  __shared__ unsigned short kv[WKV * LDK];   // 39168 B
  __shared__ float qs[QB * DHEAD];           //  4096 B
  __shared__ float sc[QB * WKV];             // 17408 B

  const int tid = threadIdx.x;
  const int blk = blockIdx.x;
  const int qt = blk & (T_SEQ / QB - 1);
  const int bh = blk >> 7;
  const int qBase = qt * QB;
  const int lo = max(0, qBase - 127);
  const int hi = min(T_SEQ - 1, qBase + QB - 1 + 128);
  const int nk = hi - lo + 1;
  const size_t hbase = (size_t)bh * T_SEQ * DHEAD;

  const unsigned short* qptr = Qg + hbase + (size_t)qBase * DHEAD;
  for (int idx = tid; idx < QB * DHEAD; idx += 256) qs[idx] = bf2f(qptr[idx]);
  const unsigned short* kptr = Kg + hbase + (size_t)lo * DHEAD;
  const int tot = nk * DHEAD;
  for (int e = tid * 2; e < tot; e += 512) {
    int j = e >> 6, d = e & 63;
    *(unsigned int*)&kv[j * LDK + d] = *(const unsigned int*)&kptr[e];
  }
  __syncthreads();

  const int q  = tid >> 4;
  const int ks = tid & 15;
  const int qg = qBase + q;

  float qreg[DHEAD];
  #pragma unroll
  for (int c4 = 0; c4 < DHEAD / 4; c4++) {
    floatx4 t4 = *(const floatx4*)&qs[q * DHEAD + c4 * 4];
    qreg[c4 * 4 + 0] = t4.x; qreg[c4 * 4 + 1] = t4.y;
    qreg[c4 * 4 + 2] = t4.z; qreg[c4 * 4 + 3] = t4.w;
  }

  float lmax = -3e38f;
  for (int j = ks; j < nk; j += 16) {
    float dot = 0.f;
    #pragma unroll
    for (int c = 0; c < 8; c++) {
      bf16x8 kvv = *(const bf16x8*)&kv[j * LDK + c * 8];
      #pragma unroll
      for (int u = 0; u < 8; u++)
        dot += qreg[c * 8 + u] * bf2f((unsigned short)kvv[u]);
    }
    int kg = lo + j;
    float s = (kg >= qg - 127 && kg <= qg + 128) ? dot * 0.125f : -3e38f;
    sc[q * WKV + j] = s;
    lmax = fmaxf(lmax, s);
  }
  __syncthreads();   // all K reads done -> kv reusable

  const unsigned short* vptr = Vg + hbase + (size_t)lo * DHEAD;
  for (int e = tid * 2; e < tot; e += 512) {
    int j = e >> 6, d = e & 63;
    *(unsigned int*)&kv[j * LDK + d] = *(const unsigned int*)&vptr[e];
  }

  #pragma unroll
  for (int m = 1; m <= 8; m <<= 1) lmax = fmaxf(lmax, __shfl_xor(lmax, m));
  float lsum = 0.f;
  for (int j = ks; j < nk; j += 16) {
    float p = __expf(sc[q * WKV + j] - lmax);
    sc[q * WKV + j] = p;
    lsum += p;
  }
  #pragma unroll
  for (int m = 1; m <= 8; m <<= 1) lsum += __shfl_xor(lsum, m);
  const float inv = 1.f / lsum;
  __syncthreads();   // V staged + all p visible

  float a0 = 0.f, a1 = 0.f, a2 = 0.f, a3 = 0.f;
  const float* pr = &sc[q * WKV];
  for (int j = 0; j < nk; j++) {
    float p = pr[j];
    bf16x4 vv = *(const bf16x4*)&kv[j * LDK + ks * 4];
    a0 += p * bf2f((unsigned short)vv[0]);
    a1 += p * bf2f((unsigned short)vv[1]);
    a2 += p * bf2f((unsigned short)vv[2]);
    a3 += p * bf2f((unsigned short)vv[3]);
  }
  const int b = bh >> 4, h = bh & 15;
  size_t ob = ((size_t)(b * T_SEQ + qg)) * DMODEL + h * DHEAD + ks * 4;
  Og[ob + 0] = f2bf(a0 * inv);
  Og[ob + 1] = f2bf(a1 * inv);
  Og[ob + 2] = f2bf(a2 * inv);
  Og[ob + 3] = f2bf(a3 * inv);
}

// ---------------------------------------------------------------------------
// out = rmsnorm(a + ALPHA*xres, g). a bf16; xres f32/bf16; g f32; out f32/bf16.
// ---------------------------------------------------------------------------
template<bool XRES_F32, bool OUT_F32>
__global__ __launch_bounds__(256) void resid_rmsnorm(
    const unsigned short* __restrict__ a,
    const void* __restrict__ xresp,
    const float* __restrict__ g,
    void* __restrict__ outp)
{
  __shared__ float red[4];
  const int row = blockIdx.x;
  const int tid = threadIdx.x;
  const size_t base = (size_t)row * DMODEL;
  float s[4];
  float ss = 0.f;
  #pragma unroll
  for (int r = 0; r < 4; r++) {
    int c = r * 256 + tid;
    float xr = XRES_F32 ? ((const float*)xresp)[base + c]
                        : bf2f(((const unsigned short*)xresp)[base + c]);
    float vv = bf2f(a[base + c]) + ALPHA_C * xr;
    s[r] = vv;
    ss += vv * vv;
  }
  #pragma unroll
  for (int m = 1; m <= 32; m <<= 1) ss += __shfl_xor(ss, m);
  if ((tid & 63) == 0) red[tid >> 6] = ss;
  __syncthreads();
  float ms = (red[0] + red[1] + red[2] + red[3]) * (1.f / DMODEL);
  float scl = rsqrtf(ms + EPS_C);
  #pragma unroll
  for (int r = 0; r < 4; r++) {
    int c = r * 256 + tid;
    float o = s[r] * scl * g[c];
    if (OUT_F32) ((float*)outp)[base + c] = o;
    else ((unsigned short*)outp)[base + c] = f2bf(o);
  }
}

// ---------------------------------------------------------------------------
// SwiGLU in place: yg[r,c] = y * gate * sigmoid(gate), gate = yg[r,4096+c].
// ---------------------------------------------------------------------------
__global__ void swiglu_kernel(unsigned short* __restrict__ yg)
{
  int gid = blockIdx.x * 256 + threadIdx.x;
  int row = gid >> 12, c = gid & 4095;
  size_t b = (size_t)row * 8192;
  float y  = bf2f(yg[b + c]);
  float gt = bf2f(yg[b + 4096 + c]);
  float sig = 1.f / (1.f + __expf(-gt));
  yg[b + c] = f2bf(y * gt * sig);
}

// ---------------------------------------------------------------------------
// Workspace plan (bf16 elems), peak 58,720,256 elems = 112 MiB:
//   [0,        16.78M)  bf16 weights: Wqkvb, Woutb, W1b, W2b   (persistent)
//   [16.78M,   20.97M)  P1: xb -> tmp -> tmp2                  (serial reuse)
//   [20.97M,   25.17M)  x2                                     (step5..end)
//   [25.17M,   37.75M)  qkv (steps1-2) -> o (3-4) -> yg[0:12.6M) (6-8)
//   [37.75M,   50.33M)  q,k,v (steps2-3) -> yg[12.6M:25.2M)
//   [50.33M,   58.72M)  yg tail
// ---------------------------------------------------------------------------
extern "C" void kernel_launch(void* const* d_in, const int* in_sizes, int n_in,
                              void* d_out, int out_size, void* d_ws, size_t ws_size,
                              hipStream_t stream) {
  (void)in_sizes; (void)n_in; (void)out_size; (void)ws_size;
  const float* x    = (const float*)d_in[0];
  const float* Wqkv = (const float*)d_in[1];
  const float* Wout = (const float*)d_in[2];
  const float* bout = (const float*)d_in[3];
  const float* W1   = (const float*)d_in[4];
  const float* W2   = (const float*)d_in[5];
  const float* g1   = (const float*)d_in[6];
  const float* g2   = (const float*)d_in[7];
  float* out = (float*)d_out;

  unsigned short* ws    = (unsigned short*)d_ws;
  unsigned short* Wqkvb = ws;                    //  3,145,728
  unsigned short* Woutb = ws + 3145728;          //  1,048,576
  unsigned short* W1b   = ws + 4194304;          //  8,388,608
  unsigned short* W2b   = ws + 12582912;         //  4,194,304
  unsigned short* P1    = ws + 16777216;         //  4,194,304 (xb/tmp/tmp2)
  unsigned short* x2    = ws + 20971520;         //  4,194,304
  unsigned short* qkv   = ws + 25165824;         // 12,582,912
  unsigned short* q     = ws + 37748736;         //  4,194,304
  unsigned short* k     = ws + 41943040;
  unsigned short* v     = ws + 46137344;
  unsigned short* o     = ws + 25165824;         // alias qkv (dead)
  unsigned short* yg    = ws + 25165824;         // 33,554,432 (qkv,q,k,v dead)

  // 0. f32 -> bf16 conversions (weights + x)
  f32_to_bf16<<<1536, 256, 0, stream>>>(Wqkv, Wqkvb);
  f32_to_bf16<<< 512, 256, 0, stream>>>(Wout, Woutb);
  f32_to_bf16<<<4096, 256, 0, stream>>>(W1, W1b);
  f32_to_bf16<<<2048, 256, 0, stream>>>(W2, W2b);
  f32_to_bf16<<<2048, 256, 0, stream>>>(x, P1);
  // 1. qkv = x @ Wqkv^T                          [4096,3072]
  gemm_lds<128><<<dim3(3072 / 128, 32), 256, 0, stream>>>(P1, Wqkvb, qkv, nullptr, 4096, 3072, 1024, 1024);
  // 2. rope + split into q,k,v [B*H,T,64]
  rope_split<<<8192, 256, 0, stream>>>(qkv, q, k, v);
  // 3. banded attention -> o [B,T,1024]
  attn_banded<<<32 * (T_SEQ / QB), 256, 0, stream>>>(q, k, v, o);
  // 4. a = o @ Wout^T + bout -> tmp (P1)
  gemm_lds<64><<<dim3(1024 / 64, 32), 256, 0, stream>>>(o, Woutb, P1, bout, 4096, 1024, 1024, 1024);
  // 5. x2 = rmsnorm(a + ALPHA*x, g1)   (x f32, x2 bf16)
  resid_rmsnorm<true, false><<<4096, 256, 0, stream>>>(P1, x, g1, x2);
  // 6. yg = x2 @ W1^T                            [4096,8192]
  gemm_lds<128><<<dim3(8192 / 128, 32), 256, 0, stream>>>(x2, W1b, yg, nullptr, 4096, 8192, 1024, 1024);
  // 7. swiglu in place (first 4096 cols of yg)
  swiglu_kernel<<<65536, 256, 0, stream>>>(yg);
  // 8. y2 = ys @ W2^T -> tmp2 (P1)   (A = yg, lda=8192)
  gemm_lds<64><<<dim3(1024 / 64, 32), 256, 0, stream>>>(yg, W2b, P1, nullptr, 4096, 1024, 4096, 8192);
  // 9. out = rmsnorm(y2 + ALPHA*x2, g2)  (x2 bf16, out f32)
  resid_rmsnorm<false, true><<<4096, 256, 0, stream>>>(P1, x2, g2, out);
}

// Round 5
// 469.920 us; speedup vs baseline: 1.5284x; 1.2207x over previous
//
#include <hip/hip_runtime.h>

#define T_SEQ   2048
#define NHEADS  16
#define DHEAD   64
#define DMODEL  1024
#define ALPHA_C 1.4142135f
#define EPS_C   1e-5f

typedef __attribute__((ext_vector_type(8))) short bf16x8;
typedef __attribute__((ext_vector_type(4))) short bf16x4;
typedef __attribute__((ext_vector_type(4))) float floatx4;

__device__ __forceinline__ float bf2f(unsigned short u) {
  union { unsigned int i; float f; } v;
  v.i = ((unsigned int)u) << 16;
  return v.f;
}
__device__ __forceinline__ unsigned short f2bf(float f) {
  union { float f; unsigned int i; } v;
  v.f = f;
  unsigned int u = v.i;
  u += 0x7FFF + ((u >> 16) & 1);   // RNE (finite data only)
  return (unsigned short)(u >> 16);
}

__device__ __forceinline__ void gload_lds16(const void* g, void* l) {
  __builtin_amdgcn_global_load_lds(
      (const __attribute__((address_space(1))) void*)g,
      (__attribute__((address_space(3))) void*)l, 16, 0, 0);
}

// ---------------------------------------------------------------------------
// f32 -> bf16 bulk convert (8 elems/thread, n % 2048 == 0)
// ---------------------------------------------------------------------------
__global__ void f32_to_bf16(const float* __restrict__ in,
                            unsigned short* __restrict__ out)
{
  int i = (blockIdx.x * 256 + threadIdx.x) * 8;
  floatx4 a = *(const floatx4*)(in + i);
  floatx4 b = *(const floatx4*)(in + i + 4);
  bf16x8 o;
  #pragma unroll
  for (int u = 0; u < 4; u++) {
    o[u]     = (short)f2bf(a[u]);
    o[4 + u] = (short)f2bf(b[u]);
  }
  *(bf16x8*)(out + i) = o;
}

// ---------------------------------------------------------------------------
// GEMM (m97 structure): C[M,N] = A[M,K] @ W[N,K]^T (+ bias), all bf16,
// fp32 accum. BM=128, BK=32, BN templated. global_load_lds width=16,
// unpadded lane-contiguous LDS tiles, ds_read_b128 fragments.
// ---------------------------------------------------------------------------
template<int BN>
__global__ __launch_bounds__(256) void gemm_lds(
    const unsigned short* __restrict__ A,
    const unsigned short* __restrict__ W,
    unsigned short* __restrict__ C,
    const float* __restrict__ bias,
    int M, int N, int K, int lda)
{
  constexpr int WN = BN / 2;
  constexpr int NJ = WN / 16;
  __shared__ unsigned short As[128 * 32];
  __shared__ unsigned short Bs[BN * 32];

  const int tid  = threadIdx.x;
  const int lane = tid & 63;
  const int wave = tid >> 6;
  const int wm = (wave >> 1) * 64;
  const int wn = (wave & 1) * WN;
  const int mBase = blockIdx.y * 128;
  const int nBase = blockIdx.x * BN;

  const int sRow = lane >> 2;
  const int sCol = (lane & 3) * 8;

  floatx4 acc[4][NJ];
  #pragma unroll
  for (int i = 0; i < 4; i++)
    #pragma unroll
    for (int j = 0; j < NJ; j++) acc[i][j] = (floatx4){0.f, 0.f, 0.f, 0.f};

  const int mrow = lane & 15;
  const int kq   = (lane >> 4) * 8;

  for (int kb = 0; kb < K; kb += 32) {
    __syncthreads();
    #pragma unroll
    for (int j = 0; j < 2; j++) {
      int r = wave * 32 + j * 16 + sRow;
      gload_lds16(A + (size_t)(mBase + r) * lda + kb + sCol,
                  &As[wave * 1024 + j * 512 + lane * 8]);
    }
    if constexpr (BN == 128) {
      #pragma unroll
      for (int j = 0; j < 2; j++) {
        int r = wave * 32 + j * 16 + sRow;
        gload_lds16(W + (size_t)(nBase + r) * K + kb + sCol,
                    &Bs[wave * 1024 + j * 512 + lane * 8]);
      }
    } else {
      int r = wave * 16 + sRow;
      gload_lds16(W + (size_t)(nBase + r) * K + kb + sCol,
                  &Bs[wave * 512 + lane * 8]);
    }
    __syncthreads();

    bf16x8 af[4], bfr[NJ];
    #pragma unroll
    for (int i = 0; i < 4; i++)
      af[i] = *(const bf16x8*)&As[(wm + i * 16 + mrow) * 32 + kq];
    #pragma unroll
    for (int j = 0; j < NJ; j++)
      bfr[j] = *(const bf16x8*)&Bs[(wn + j * 16 + mrow) * 32 + kq];
    #pragma unroll
    for (int i = 0; i < 4; i++)
      #pragma unroll
      for (int j = 0; j < NJ; j++)
        acc[i][j] = __builtin_amdgcn_mfma_f32_16x16x32_bf16(af[i], bfr[j], acc[i][j], 0, 0, 0);
  }

  const int col0 = lane & 15;
  const int row0 = (lane >> 4) * 4;
  #pragma unroll
  for (int j = 0; j < NJ; j++) {
    const int col = nBase + wn + j * 16 + col0;
    const float badd = bias ? bias[col] : 0.f;
    #pragma unroll
    for (int i = 0; i < 4; i++) {
      #pragma unroll
      for (int r = 0; r < 4; r++) {
        const int row = mBase + wm + i * 16 + row0 + r;
        C[(size_t)row * N + col] = f2bf(acc[i][j][r] + badd);
      }
    }
  }
}

// ---------------------------------------------------------------------------
// RoPE + split: qkv[B,T,3,H,D] (bf16) -> q,k (roped), v in [B*H, T, D] bf16.
// ---------------------------------------------------------------------------
__global__ void rope_split(const unsigned short* __restrict__ qkv,
                           unsigned short* __restrict__ q,
                           unsigned short* __restrict__ k,
                           unsigned short* __restrict__ v)
{
  int gid = blockIdx.x * 256 + threadIdx.x;
  if (gid >= 2 * NHEADS * T_SEQ * 32) return;
  int i  = gid & 31;
  int t  = (gid >> 5) & (T_SEQ - 1);
  int bh = gid >> 16;
  int b = bh >> 4, h = bh & 15;
  size_t inb = ((size_t)(b * T_SEQ + t)) * 3072 + h * DHEAD;
  float fr = powf(10000.f, -(float)i * (1.f / 32.f));
  float ang = (float)t * fr;
  float sn, cs;
  sincosf(ang, &sn, &cs);
  float q1 = bf2f(qkv[inb + i]),        q2 = bf2f(qkv[inb + 32 + i]);
  float k1 = bf2f(qkv[inb + 1024 + i]), k2 = bf2f(qkv[inb + 1024 + 32 + i]);
  size_t ob = ((size_t)bh * T_SEQ + t) * DHEAD + i;
  q[ob]      = f2bf(q1 * cs - q2 * sn);
  q[ob + 32] = f2bf(q2 * cs + q1 * sn);
  k[ob]      = f2bf(k1 * cs - k2 * sn);
  k[ob + 32] = f2bf(k2 * cs + k1 * sn);
  v[ob]      = qkv[inb + 2048 + i];
  v[ob + 32] = qkv[inb + 2048 + 32 + i];
}

// ---------------------------------------------------------------------------
// MFMA banded attention. Block = 64 queries of one (b,h), 4 waves, wave w
// owns queries [16w,16w+16). Fixed 320-slot key window koff -> kg =
// qBase-127+koff (clamped loads, masked scores; band rel in [-127,128] <=>
// 0 <= koff - qrow_in_block <= 255).
//  QK^T: A=Q frags (regs), B=K tile in LDS [320][72] -> 20x2 MFMA 16x16x32.
//  Softmax: C-layout (query=quad*4+reg, key=lane&15) -> shfl over quad.
//  P -> LDS [16][328] bf16 per wave (A-operand layout).
//  V^T -> LDS [64][328] (reuses K tile region) as B operand; PV: 4x10 MFMA.
// LDS total 97,280 B -> 1 block/CU.
// ---------------------------------------------------------------------------
__global__ __launch_bounds__(256) void attn_mfma(
    const unsigned short* __restrict__ Qg,
    const unsigned short* __restrict__ Kg,
    const unsigned short* __restrict__ Vg,
    unsigned short* __restrict__ Og)
{
  __shared__ unsigned short KV[23040];   // K tile [320][72]; then V^T [64][328]
  __shared__ unsigned short Qs[64 * 72];
  __shared__ unsigned short Ps[4 * 16 * 328];

  const int tid  = threadIdx.x;
  const int lane = tid & 63;
  const int wave = tid >> 6;
  const int c    = lane & 15;        // C-layout col / fragment m,n index
  const int quad = lane >> 4;
  const int blk  = blockIdx.x;
  const int bh   = blk >> 5;
  const int qBase = (blk & 31) * 64;
  const size_t hbase = (size_t)bh * T_SEQ * DHEAD;

  // ---- stage K window [320][72] and Q tile [64][72] ----
  for (int e = tid; e < 320 * 8; e += 256) {
    int row = e >> 3, ch = e & 7;
    int kg = qBase - 127 + row;
    int kgc = min(max(kg, 0), T_SEQ - 1);
    *(bf16x8*)&KV[row * 72 + ch * 8] =
        *(const bf16x8*)(Kg + hbase + (size_t)kgc * DHEAD + ch * 8);
  }
  for (int e = tid; e < 64 * 8; e += 256) {
    int row = e >> 3, ch = e & 7;
    *(bf16x8*)&Qs[row * 72 + ch * 8] =
        *(const bf16x8*)(Qg + hbase + (size_t)(qBase + row) * DHEAD + ch * 8);
  }
  __syncthreads();

  // ---- Q fragments (regs): A[m=c][k=half*32 + quad*8] ----
  bf16x8 aq[2];
  #pragma unroll
  for (int hh = 0; hh < 2; hh++)
    aq[hh] = *(const bf16x8*)&Qs[(wave * 16 + c) * 72 + hh * 32 + quad * 8];

  // ---- QK^T: 20 key tiles ----
  floatx4 s[20];
  #pragma unroll
  for (int kt = 0; kt < 20; kt++) {
    bf16x8 b0 = *(const bf16x8*)&KV[(kt * 16 + c) * 72 + quad * 8];
    bf16x8 b1 = *(const bf16x8*)&KV[(kt * 16 + c) * 72 + 32 + quad * 8];
    floatx4 t = (floatx4){0.f, 0.f, 0.f, 0.f};
    t = __builtin_amdgcn_mfma_f32_16x16x32_bf16(aq[0], b0, t, 0, 0, 0);
    t = __builtin_amdgcn_mfma_f32_16x16x32_bf16(aq[1], b1, t, 0, 0, 0);
    s[kt] = t;
  }
  __syncthreads();   // all K-tile LDS reads done -> KV reusable for V^T

  // ---- stage V^T [64][328] over KV (scalar transpose writes) ----
  for (int ch = wave; ch < 5; ch += 4) {
    int koff = ch * 64 + lane;
    int kg = qBase - 127 + koff;
    int kgc = min(max(kg, 0), T_SEQ - 1);
    const unsigned short* vrow = Vg + hbase + (size_t)kgc * DHEAD;
    #pragma unroll
    for (int dg = 0; dg < 8; dg++) {
      bf16x8 v8 = *(const bf16x8*)(vrow + dg * 8);
      #pragma unroll
      for (int j = 0; j < 8; j++)
        KV[(dg * 8 + j) * 328 + koff] = (unsigned short)v8[j];
    }
  }

  // ---- mask + scale + softmax (regs; query = quad*4+reg) ----
  const int kLoMin = max(0, 127 - qBase);
  const int kHiMax = min(319, 2047 + 127 - qBase);
  float mx[4] = {-3e38f, -3e38f, -3e38f, -3e38f};
  #pragma unroll
  for (int kt = 0; kt < 20; kt++) {
    const int koff = kt * 16 + c;
    #pragma unroll
    for (int reg = 0; reg < 4; reg++) {
      const int qrow = wave * 16 + quad * 4 + reg;
      const int d = koff - qrow;
      bool ok = (d >= 0) && (d <= 255) && (koff >= kLoMin) && (koff <= kHiMax);
      float val = ok ? s[kt][reg] * 0.125f : -3e38f;
      s[kt][reg] = val;
      mx[reg] = fmaxf(mx[reg], val);
    }
  }
  #pragma unroll
  for (int reg = 0; reg < 4; reg++)
    #pragma unroll
    for (int m = 1; m <= 8; m <<= 1)
      mx[reg] = fmaxf(mx[reg], __shfl_xor(mx[reg], m));

  float ls[4] = {0.f, 0.f, 0.f, 0.f};
  #pragma unroll
  for (int kt = 0; kt < 20; kt++) {
    const int koff = kt * 16 + c;
    #pragma unroll
    for (int reg = 0; reg < 4; reg++) {
      float p = __expf(s[kt][reg] - mx[reg]);
      ls[reg] += p;
      Ps[wave * 5248 + (quad * 4 + reg) * 328 + koff] = f2bf(p);
    }
  }
  float inv[4];
  #pragma unroll
  for (int reg = 0; reg < 4; reg++) {
    #pragma unroll
    for (int m = 1; m <= 8; m <<= 1) ls[reg] += __shfl_xor(ls[reg], m);
    inv[reg] = 1.f / ls[reg];
  }
  __syncthreads();   // V^T staged + P visible

  // ---- PV: C[query][dim] = sum_key P[query][key] * Vt[dim][key] ----
  floatx4 oacc[4];
  #pragma unroll
  for (int nt = 0; nt < 4; nt++) oacc[nt] = (floatx4){0.f, 0.f, 0.f, 0.f};
  #pragma unroll
  for (int kt2 = 0; kt2 < 10; kt2++) {
    bf16x8 a = *(const bf16x8*)&Ps[wave * 5248 + c * 328 + kt2 * 32 + quad * 8];
    #pragma unroll
    for (int nt = 0; nt < 4; nt++) {
      bf16x8 bb = *(const bf16x8*)&KV[(nt * 16 + c) * 328 + kt2 * 32 + quad * 8];
      oacc[nt] = __builtin_amdgcn_mfma_f32_16x16x32_bf16(a, bb, oacc[nt], 0, 0, 0);
    }
  }

  // ---- store O [B,T,1024] ----
  const int b = bh >> 4, h = bh & 15;
  #pragma unroll
  for (int nt = 0; nt < 4; nt++) {
    #pragma unroll
    for (int reg = 0; reg < 4; reg++) {
      const int qg = qBase + wave * 16 + quad * 4 + reg;
      Og[((size_t)(b * T_SEQ + qg)) * DMODEL + h * DHEAD + nt * 16 + c] =
          f2bf(oacc[nt][reg] * inv[reg]);
    }
  }
}

// ---------------------------------------------------------------------------
// out = rmsnorm(a + ALPHA*xres, g). a bf16; xres f32/bf16; g f32; out f32/bf16.
// ---------------------------------------------------------------------------
template<bool XRES_F32, bool OUT_F32>
__global__ __launch_bounds__(256) void resid_rmsnorm(
    const unsigned short* __restrict__ a,
    const void* __restrict__ xresp,
    const float* __restrict__ g,
    void* __restrict__ outp)
{
  __shared__ float red[4];
  const int row = blockIdx.x;
  const int tid = threadIdx.x;
  const size_t base = (size_t)row * DMODEL;
  float s[4];
  float ss = 0.f;
  #pragma unroll
  for (int r = 0; r < 4; r++) {
    int c = r * 256 + tid;
    float xr = XRES_F32 ? ((const float*)xresp)[base + c]
                        : bf2f(((const unsigned short*)xresp)[base + c]);
    float vv = bf2f(a[base + c]) + ALPHA_C * xr;
    s[r] = vv;
    ss += vv * vv;
  }
  #pragma unroll
  for (int m = 1; m <= 32; m <<= 1) ss += __shfl_xor(ss, m);
  if ((tid & 63) == 0) red[tid >> 6] = ss;
  __syncthreads();
  float ms = (red[0] + red[1] + red[2] + red[3]) * (1.f / DMODEL);
  float scl = rsqrtf(ms + EPS_C);
  #pragma unroll
  for (int r = 0; r < 4; r++) {
    int c = r * 256 + tid;
    float o = s[r] * scl * g[c];
    if (OUT_F32) ((float*)outp)[base + c] = o;
    else ((unsigned short*)outp)[base + c] = f2bf(o);
  }
}

// ---------------------------------------------------------------------------
// SwiGLU in place: yg[r,c] = y * gate * sigmoid(gate), gate = yg[r,4096+c].
// ---------------------------------------------------------------------------
__global__ void swiglu_kernel(unsigned short* __restrict__ yg)
{
  int gid = blockIdx.x * 256 + threadIdx.x;
  int row = gid >> 12, c = gid & 4095;
  size_t b = (size_t)row * 8192;
  float y  = bf2f(yg[b + c]);
  float gt = bf2f(yg[b + 4096 + c]);
  float sig = 1.f / (1.f + __expf(-gt));
  yg[b + c] = f2bf(y * gt * sig);
}

// ---------------------------------------------------------------------------
// Workspace plan (bf16 elems), peak 58,720,256 elems = 112 MiB.
// ---------------------------------------------------------------------------
extern "C" void kernel_launch(void* const* d_in, const int* in_sizes, int n_in,
                              void* d_out, int out_size, void* d_ws, size_t ws_size,
                              hipStream_t stream) {
  (void)in_sizes; (void)n_in; (void)out_size; (void)ws_size;
  const float* x    = (const float*)d_in[0];
  const float* Wqkv = (const float*)d_in[1];
  const float* Wout = (const float*)d_in[2];
  const float* bout = (const float*)d_in[3];
  const float* W1   = (const float*)d_in[4];
  const float* W2   = (const float*)d_in[5];
  const float* g1   = (const float*)d_in[6];
  const float* g2   = (const float*)d_in[7];
  float* out = (float*)d_out;

  unsigned short* ws    = (unsigned short*)d_ws;
  unsigned short* Wqkvb = ws;                    //  3,145,728
  unsigned short* Woutb = ws + 3145728;          //  1,048,576
  unsigned short* W1b   = ws + 4194304;          //  8,388,608
  unsigned short* W2b   = ws + 12582912;         //  4,194,304
  unsigned short* P1    = ws + 16777216;         //  4,194,304 (xb/tmp/tmp2)
  unsigned short* x2    = ws + 20971520;         //  4,194,304
  unsigned short* qkv   = ws + 25165824;         // 12,582,912
  unsigned short* q     = ws + 37748736;         //  4,194,304
  unsigned short* k     = ws + 41943040;
  unsigned short* v     = ws + 46137344;
  unsigned short* o     = ws + 25165824;         // alias qkv (dead)
  unsigned short* yg    = ws + 25165824;         // 33,554,432 (qkv,q,k,v dead)

  // 0. f32 -> bf16 conversions (weights + x)
  f32_to_bf16<<<1536, 256, 0, stream>>>(Wqkv, Wqkvb);
  f32_to_bf16<<< 512, 256, 0, stream>>>(Wout, Woutb);
  f32_to_bf16<<<4096, 256, 0, stream>>>(W1, W1b);
  f32_to_bf16<<<2048, 256, 0, stream>>>(W2, W2b);
  f32_to_bf16<<<2048, 256, 0, stream>>>(x, P1);
  // 1. qkv = x @ Wqkv^T                          [4096,3072]
  gemm_lds<128><<<dim3(3072 / 128, 32), 256, 0, stream>>>(P1, Wqkvb, qkv, nullptr, 4096, 3072, 1024, 1024);
  // 2. rope + split into q,k,v [B*H,T,64]
  rope_split<<<8192, 256, 0, stream>>>(qkv, q, k, v);
  // 3. MFMA banded attention -> o [B,T,1024]
  attn_mfma<<<32 * (T_SEQ / 64), 256, 0, stream>>>(q, k, v, o);
  // 4. a = o @ Wout^T + bout -> tmp (P1)
  gemm_lds<64><<<dim3(1024 / 64, 32), 256, 0, stream>>>(o, Woutb, P1, bout, 4096, 1024, 1024, 1024);
  // 5. x2 = rmsnorm(a + ALPHA*x, g1)   (x f32, x2 bf16)
  resid_rmsnorm<true, false><<<4096, 256, 0, stream>>>(P1, x, g1, x2);
  // 6. yg = x2 @ W1^T                            [4096,8192]
  gemm_lds<128><<<dim3(8192 / 128, 32), 256, 0, stream>>>(x2, W1b, yg, nullptr, 4096, 8192, 1024, 1024);
  // 7. swiglu in place (first 4096 cols of yg)
  swiglu_kernel<<<65536, 256, 0, stream>>>(yg);
  // 8. y2 = ys @ W2^T -> tmp2 (P1)   (A = yg, lda=8192)
  gemm_lds<64><<<dim3(1024 / 64, 32), 256, 0, stream>>>(yg, W2b, P1, nullptr, 4096, 1024, 4096, 8192);
  // 9. out = rmsnorm(y2 + ALPHA*x2, g2)  (x2 bf16, out f32)
  resid_rmsnorm<false, true><<<4096, 256, 0, stream>>>(P1, x2, g2, out);
}